// Round 8
// baseline (185.745 us; speedup 1.0000x reference)
//
#include <hip/hip_runtime.h>

// ---------------------------------------------------------------------------
// R8: as R7 (3 nodes, occupancy-pinned) but gemm2's inner loop moves to
// v_mfma_f32_32x32x16_bf16 (2495 TF ubench vs 2176 for 16x16x32; half the
// MFMA issue slots for the same FLOP). gemm1 stays on 16x16x32 (isolated
// experiment). Layouts per cdna docs: A[m=lane&31][k=(lane>>5)*8+j];
// C/D col=lane&31, row=(reg&3)+8*(reg>>2)+4*(lane>>5).
// ---------------------------------------------------------------------------

typedef __bf16 bf16x8_t __attribute__((ext_vector_type(8)));
typedef float  f32x4_t  __attribute__((ext_vector_type(4)));
typedef float  f32x16_t __attribute__((ext_vector_type(16)));

__device__ inline unsigned short f2bf(float f) {
    __bf16 b = (__bf16)f;
    return __builtin_bit_cast(unsigned short, b);
}

// async stage of 8 rows (wave-uniform row0) from bf16 global, 16 B/lane,
// XOR-swizzled granules: LDS slot gs holds global granule gs ^ (row & 7)
__device__ inline void stage_glds(const unsigned short* gtile, int stride, int row0,
                                  unsigned short* lds, int lane) {
    const int r8 = lane >> 3;
    const int gg = (lane & 7) ^ r8;
    const unsigned short* gp = gtile + (size_t)(row0 + r8) * stride + gg * 8;
    unsigned short* lp = lds + row0 * 64;
    __builtin_amdgcn_global_load_lds((const __attribute__((address_space(1))) void*)gp,
                                     (__attribute__((address_space(3))) void*)lp,
                                     16, 0, 0);
}

__device__ inline bf16x8_t ldsfrag(const unsigned short* Ls, int row, int kb) {
    return *(const bf16x8_t*)(Ls + row * 64 + (((kb >> 3) ^ (row & 7)) * 8));
}

// ---------------- K1: fused activity-partials + all transposes -------------
__global__ void fused_prep_kernel(const float* __restrict__ x, const float* __restrict__ Wc,
                                  const float* __restrict__ Wf, float* __restrict__ part,
                                  unsigned short* __restrict__ wct, unsigned short* __restrict__ wft) {
    const int b = blockIdx.x;
    const int tid = threadIdx.x;

    if (b < 512) {
        const int chunk = b & 7;
        const int rg = b >> 3;
        const int colf4 = tid & 127;
        const int rsub = tid >> 7;
        const float4* base = (const float4*)x + (size_t)chunk * 128 + colf4;
        float s = 0.f;
        #pragma unroll 4
        for (int i = 0; i < 32; ++i) {
            int row = rg * 64 + i * 2 + rsub;
            float4 v = base[(size_t)row * 1024];
            s += fabsf(v.x) + fabsf(v.y) + fabsf(v.z) + fabsf(v.w);
        }
        #pragma unroll
        for (int off = 32; off > 0; off >>= 1) s += __shfl_down(s, off, 64);
        __shared__ float wsum[4];
        if ((tid & 63) == 0) wsum[tid >> 6] = s;
        __syncthreads();
        if (tid == 0) part[chunk * 64 + rg] = wsum[0] + wsum[1] + wsum[2] + wsum[3];
        return;
    }

    __shared__ float tile[32][33];
    const int tx = tid & 31, ty = tid >> 5;
    const float* src; unsigned short* dst; int R, C, cb, rb;
    int jj = b - 512;
    if (jj < 4096) {                       // Wf^T: (1024,4096) -> (4096,1024)
        src = Wf; dst = wft; R = 1024; C = 4096;
        cb = (jj & 127) * 32; rb = (jj >> 7) * 32;
    } else {                               // Wc[c]^T for ALL c
        jj -= 4096;
        int c = jj >> 8, t = jj & 255;
        src = Wc + (size_t)c * 262144;
        dst = wct + (size_t)c * 262144;
        R = 512; C = 512;
        cb = (t & 15) * 32; rb = (t >> 4) * 32;
    }
    #pragma unroll
    for (int i = 0; i < 4; ++i)
        tile[ty + i * 8][tx] = src[(size_t)(rb + ty + i * 8) * C + cb + tx];
    __syncthreads();
    #pragma unroll
    for (int i = 0; i < 4; ++i)
        dst[(size_t)(cb + ty + i * 8) * R + rb + tx] = f2bf(tile[tx][ty + i * 8]);
}

// ---------------- K2: GEMM1 — topk prologue + fused gather (16x16x32) ------
__global__ __launch_bounds__(256, 4)
void gemm1_kernel(const float* __restrict__ x, const unsigned short* __restrict__ wct,
                  const float* __restrict__ bc, const float* __restrict__ part,
                  unsigned short* __restrict__ h) {
    __shared__ __align__(16) unsigned char lds_raw[24576];
    unsigned short* As = (unsigned short*)lds_raw;            // 8 KB (64x64)
    unsigned short* Bs = (unsigned short*)(lds_raw + 8192);   // 16 KB (128x64)

    const int tid = threadIdx.x;
    const int wave = tid >> 6;
    const int lane = tid & 63;

    // prologue: reduce part[512] -> act[8] -> top-2 (redundant per block)
    {
        float* sred = (float*)lds_raw;
        sred[tid] = part[tid];
        sred[tid + 256] = part[tid + 256];
        __syncthreads();
        float* act8 = (float*)(lds_raw + 2048);
        if (tid < 8) {
            float a = 0.f;
            #pragma unroll
            for (int k = 0; k < 64; ++k) a += sred[tid * 64 + k];
            act8[tid] = a;
        }
        __syncthreads();
    }
    int sel0, sel1;
    {
        const float* act8 = (const float*)(lds_raw + 2048);
        float v0 = -1e30f, v1 = -1e30f; int b0 = 0, b1 = 0;
        #pragma unroll
        for (int i = 0; i < 8; ++i) {
            float v = act8[i];
            if (v > v0) { v1 = v0; b1 = b0; v0 = v; b0 = i; }
            else if (v > v1) { v1 = v; b1 = i; }
        }
        sel0 = b0; sel1 = b1;
    }
    __syncthreads();

    const int z = blockIdx.z;
    const int idxz = z ? sel1 : sel0;
    const int m0 = blockIdx.x * 64;
    const int n0 = blockIdx.y * 128;
    const int wm = (wave >> 1) * 32;
    const int wn = (wave & 1) * 64;
    const int rl = lane & 15;
    const int quad = lane >> 4;

    const float* xtile = x + (size_t)m0 * 4096 + idxz * 512;
    const unsigned short* Btile = wct + (size_t)idxz * 262144 + (size_t)n0 * 512;

    f32x4_t acc[2][4] = {};
    const int ar = tid >> 2;
    const int aq = tid & 3;

    for (int k0 = 0; k0 < 512; k0 += 64) {
        #pragma unroll
        for (int s = wave; s < 16; s += 4)
            stage_glds(Btile + k0, 512, s * 8, Bs, lane);
        const float* gr = xtile + (size_t)ar * 4096 + k0;
        #pragma unroll
        for (int j = 0; j < 2; ++j) {
            int gg = aq * 2 + j;
            float4 a = *(const float4*)(gr + gg * 8);
            float4 c = *(const float4*)(gr + gg * 8 + 4);
            bf16x8_t v;
            v[0] = (__bf16)a.x; v[1] = (__bf16)a.y; v[2] = (__bf16)a.z; v[3] = (__bf16)a.w;
            v[4] = (__bf16)c.x; v[5] = (__bf16)c.y; v[6] = (__bf16)c.z; v[7] = (__bf16)c.w;
            *(bf16x8_t*)(As + ar * 64 + ((gg ^ (ar & 7)) * 8)) = v;
        }
        __syncthreads();
        #pragma unroll
        for (int kq = 0; kq < 2; ++kq) {
            const int kb = kq * 32 + quad * 8;
            bf16x8_t af[2], bfr[4];
            #pragma unroll
            for (int i = 0; i < 2; ++i) af[i]  = ldsfrag(As, wm + i * 16 + rl, kb);
            #pragma unroll
            for (int i = 0; i < 4; ++i) bfr[i] = ldsfrag(Bs, wn + i * 16 + rl, kb);
            #pragma unroll
            for (int mi = 0; mi < 2; ++mi)
                #pragma unroll
                for (int ni = 0; ni < 4; ++ni)
                    acc[mi][ni] = __builtin_amdgcn_mfma_f32_16x16x32_bf16(af[mi], bfr[ni], acc[mi][ni], 0, 0, 0);
        }
        __syncthreads();
    }

    const int row_l = quad * 4;
    const float* bias = bc + (size_t)idxz * 512;
    #pragma unroll
    for (int ni = 0; ni < 4; ++ni) {
        int col = n0 + wn + ni * 16 + rl;
        float bv = bias[col];
        #pragma unroll
        for (int mi = 0; mi < 2; ++mi) {
            #pragma unroll
            for (int j = 0; j < 4; ++j) {
                int row = m0 + wm + mi * 16 + row_l + j;
                h[(size_t)row * 1024 + z * 512 + col] = f2bf(acc[mi][ni][j] + bv);
            }
        }
    }
}

// ---------------- K3: GEMM2 — 128x128 tile, 32x32x16 MFMA ------------------
__global__ __launch_bounds__(256, 4)
void gemm2_kernel(const unsigned short* __restrict__ h, const unsigned short* __restrict__ wft,
                  const float* __restrict__ bfin, float* __restrict__ out) {
    __shared__ __align__(16) unsigned short As[128 * 64];   // 16 KB
    __shared__ __align__(16) unsigned short Bs[128 * 64];   // 16 KB
    const int m0 = blockIdx.x * 128;
    const int n0 = blockIdx.y * 128;
    const int tid = threadIdx.x;
    const int wave = tid >> 6;
    const int lane = tid & 63;
    const int wm = (wave >> 1) * 64;   // wave's 64-row band
    const int wn = (wave & 1) * 64;    // wave's 64-col band
    const int cl = lane & 31;          // 32x32 fragment row/col index
    const int kh = (lane >> 5) * 8;    // k-offset within 16-wide k-step

    const unsigned short* Atile = h + (size_t)m0 * 1024;
    const unsigned short* Btile = wft + (size_t)n0 * 1024;

    f32x16_t acc[2][2] = {};           // 2x2 tiles of 32x32 -> 64 AGPRs

    for (int k0 = 0; k0 < 1024; k0 += 64) {
        #pragma unroll
        for (int s = wave; s < 32; s += 4) {
            if (s < 16) stage_glds(Atile + k0, 1024, s * 8, As, lane);
            else        stage_glds(Btile + k0, 1024, (s - 16) * 8, Bs, lane);
        }
        __syncthreads();
        #pragma unroll
        for (int ks = 0; ks < 4; ++ks) {           // 4 k-steps of 16
            const int kb = ks * 16 + kh;
            bf16x8_t af[2], bfr[2];
            #pragma unroll
            for (int i = 0; i < 2; ++i) {
                af[i]  = ldsfrag(As, wm + i * 32 + cl, kb);
                bfr[i] = ldsfrag(Bs, wn + i * 32 + cl, kb);
            }
            #pragma unroll
            for (int mi = 0; mi < 2; ++mi)
                #pragma unroll
                for (int ni = 0; ni < 2; ++ni)
                    acc[mi][ni] = __builtin_amdgcn_mfma_f32_32x32x16_bf16(af[mi], bfr[ni], acc[mi][ni], 0, 0, 0);
        }
        __syncthreads();
    }

    // epilogue: C/D layout col=lane&31, row=(r&3)+8*(r>>2)+4*(lane>>5)
    const int rh = (lane >> 5) * 4;
    float bv[2];
    #pragma unroll
    for (int ni = 0; ni < 2; ++ni) bv[ni] = bfin[n0 + wn + ni * 32 + cl];
    #pragma unroll
    for (int r = 0; r < 16; ++r) {
        const int rr = (r & 3) + 8 * (r >> 2) + rh;
        #pragma unroll
        for (int mi = 0; mi < 2; ++mi) {
            const int row = m0 + wm + mi * 32 + rr;
            float* orow = out + (size_t)row * 4096 + n0 + wn + cl;
            #pragma unroll
            for (int ni = 0; ni < 2; ++ni)
                orow[ni * 32] = acc[mi][ni][r] + bv[ni];
        }
    }
}

// ---------------------------------------------------------------------------
extern "C" void kernel_launch(void* const* d_in, const int* in_sizes, int n_in,
                              void* d_out, int out_size, void* d_ws, size_t ws_size,
                              hipStream_t stream) {
    const float* x    = (const float*)d_in[0];   // (4096, 4096)
    const float* Wc   = (const float*)d_in[1];   // (8, 512, 512)
    const float* bc   = (const float*)d_in[2];   // (8, 512)
    const float* Wf   = (const float*)d_in[3];   // (1024, 4096)
    const float* bfin = (const float*)d_in[4];   // (4096,)
    float* out = (float*)d_out;                  // (4096, 4096) fp32

    float* part = (float*)d_ws;                                    // 512 f32
    unsigned short* h   = (unsigned short*)((char*)d_ws + 4096);   // 4096x1024 bf16
    unsigned short* wct = h   + (size_t)4096 * 1024;               // 8x512x512 bf16
    unsigned short* wft = wct + (size_t)8 * 512 * 512;             // 4096x1024 bf16

    fused_prep_kernel<<<6656, 256, 0, stream>>>(x, Wc, Wf, part, wct, wft);
    gemm1_kernel<<<dim3(64, 4, 2), 256, 0, stream>>>(x, wct, bc, part, h);
    gemm2_kernel<<<dim3(32, 32, 1), 256, 0, stream>>>(h, wft, bfin, out);
}